// Round 3
// baseline (847.954 us; speedup 1.0000x reference)
//
#include <hip/hip_runtime.h>

#define BB 512
#define TT 256

typedef __attribute__((ext_vector_type(8)))  short bf8;   // 8 bf16 in 4 VGPRs
typedef __attribute__((ext_vector_type(4)))  short bf4;   // 4 bf16, 8B
typedef __attribute__((ext_vector_type(16))) float f16v;  // MFMA 32x32 acc
typedef __attribute__((ext_vector_type(4)))  float f4v;

#define MFMA(a,b,c) __builtin_amdgcn_mfma_f32_32x32x16_bf16((a),(b),(c),0,0,0)

__device__ __forceinline__ unsigned short f2bf(float x) {   // RNE float->bf16
    unsigned u = __builtin_bit_cast(unsigned, x);
    return (unsigned short)((u + 0x7FFFu + ((u >> 16) & 1u)) >> 16);
}
__device__ __forceinline__ float bf2f(unsigned short h) {
    unsigned u = ((unsigned)h) << 16;
    return __builtin_bit_cast(float, u);
}
__device__ __forceinline__ bf8 ld8(const unsigned short* p) {  // 2x ds_read_b64
    bf4 a = *(const bf4*)p;
    bf4 b = *(const bf4*)(p + 4);
    bf8 r;
    r[0]=a[0]; r[1]=a[1]; r[2]=a[2]; r[3]=a[3];
    r[4]=b[0]; r[5]=b[1]; r[6]=b[2]; r[7]=b[3];
    return r;
}

// One chain per wave. Block = 64 threads = 1 wave. No inter-wave communication.
// C-layout (32x32x16 MFMA, verified m74/m101): lane holds col c=lane&31,
// rows (reg&3)+8*(reg>>2)+4*(lane>>5). A/B-frag: lane holds [lane&31][k=(lane>>5)*8+j].
__global__ __launch_bounds__(64, 1)
void kalman_wave(const float* __restrict__ obs,       // [B,T,4]
                 const float* __restrict__ Fg,        // [32,32]
                 const float* __restrict__ Qg,        // [32,32]
                 const float* __restrict__ Hg,        // [4,32]
                 const float* __restrict__ Rg,        // [4,4]
                 const float* __restrict__ init_mean, // [B,32]
                 const float* __restrict__ init_cov,  // [B,32,32]
                 float* __restrict__ out)              // means [T,B,4] ++ covs [T,B,4,4]
{
    // bf16 [row][k] storage, stride 36 (72B rows: 8B-aligned runs, 2-way banks max)
    __shared__ __align__(16) unsigned short sPBh[32*36], sPBl[32*36]; // P   (symmetric store)
    __shared__ __align__(16) unsigned short sWBh[32*36], sWBl[32*36]; // P_u then T'
    __shared__ __align__(16) unsigned short sPNh[4*36],  sPNl[4*36];  // sPN[n][k] = PHt[k][n]
    __shared__ __align__(16) float sFf[32*40];  // F rows fp32 (stride 40: 2-way banks)
    __shared__ __align__(16) float sHf[4*40];
    __shared__ __align__(16) float sm[32], smu[32];
    __shared__ __align__(16) float sresid[4], sSm[16];

    const int lane = threadIdx.x;
    const int b    = blockIdx.x;
    const int c    = lane & 31;   // column owned (C-layout) / frag row index
    const int h    = lane >> 5;   // wave half

    // ---- constant fragments: F and H, split bf16 hi/lo, both K-halves ----
    bf8 Fh[2], Fl[2], Hh[2], Hl[2];
    #pragma unroll
    for (int kk = 0; kk < 2; ++kk) {
        #pragma unroll
        for (int j = 0; j < 8; ++j) {
            int k = kk*16 + h*8 + j;
            float f = Fg[c*32 + k];
            unsigned short fh = f2bf(f);
            Fh[kk][j] = (short)fh;
            Fl[kk][j] = (short)f2bf(f - bf2f(fh));
            float hv = (c < 4) ? Hg[c*32 + k] : 0.f;
            unsigned short hh = f2bf(hv);
            Hh[kk][j] = (short)hh;
            Hl[kk][j] = (short)f2bf(hv - bf2f(hh));
        }
    }

    // ---- Q and P in C-layout registers ----
    f16v Qc, P;
    #pragma unroll
    for (int reg = 0; reg < 16; ++reg) {
        int row = (reg & 3) + 8*(reg >> 2) + 4*h;
        Qc[reg] = Qg[row*32 + c];
        P[reg]  = init_cov[(size_t)b*1024 + row*32 + c];
    }
    float Rc[4] = {0.f, 0.f, 0.f, 0.f};
    if (c < 4) {
        #pragma unroll
        for (int m = 0; m < 4; ++m) Rc[m] = Rg[m*4 + c];
    }
    float mreg = (lane < 32) ? init_mean[b*32 + lane] : 0.f;
    if (lane < 32) sm[lane] = mreg;

    // ---- stage F/H fp32 into LDS ----
    #pragma unroll
    for (int e = lane; e < 1024; e += 64) sFf[(e >> 5)*40 + (e & 31)] = Fg[e];
    if (lane < 64) { int e = lane; if (e < 128) sHf[(e >> 5)*40 + (e & 31)] = Hg[e]; }
    { int e = lane + 64; if (e < 128) sHf[(e >> 5)*40 + (e & 31)] = Hg[e]; }

    // ---- write initial P bf16 frag storage (symmetric: store col c as row c) ----
    #pragma unroll
    for (int q = 0; q < 4; ++q) {
        int r0 = 8*q + 4*h;
        bf4 vh, vl;
        #pragma unroll
        for (int i = 0; i < 4; ++i) {
            float x = P[4*q + i];
            unsigned short hh = f2bf(x);
            vh[i] = (short)hh;
            vl[i] = (short)f2bf(x - bf2f(hh));
        }
        *(bf4*)&sPBh[c*36 + r0] = vh;
        *(bf4*)&sPBl[c*36 + r0] = vl;
    }
    __syncthreads();

    float* out_means = out;
    float* out_covs  = out + (size_t)TT * BB * 4;

    for (int t = 0; t < TT; ++t) {
        // prefetch observation (used late in the step)
        float yv = 0.f;
        if (lane < 4) yv = obs[((size_t)b*TT + t)*4 + lane];

        // ===== PHt = (H*P)^T via MFMA: lanes<32 get PHt[c][0..3] in regs =====
        bf8 Pbh[2], Pbl[2];
        #pragma unroll
        for (int kk = 0; kk < 2; ++kk) {
            int k0 = kk*16 + h*8;
            Pbh[kk] = ld8(&sPBh[c*36 + k0]);
            Pbl[kk] = ld8(&sPBl[c*36 + k0]);
        }
        f16v accA = 0.0f, accB = 0.0f;
        accA = MFMA(Hh[0], Pbh[0], accA);
        accB = MFMA(Hh[1], Pbh[1], accB);
        accA = MFMA(Hh[0], Pbl[0], accA);
        accB = MFMA(Hh[1], Pbl[1], accB);
        accA = MFMA(Hl[0], Pbh[0], accA);
        accB = MFMA(Hl[1], Pbh[1], accB);
        float PHt0 = accA[0] + accB[0];
        float PHt1 = accA[1] + accB[1];
        float PHt2 = accA[2] + accB[2];
        float PHt3 = accA[3] + accB[3];

        // scatter PHt as bf16 into sPN[n][k=lane]  (lanes<32)
        if (lane < 32) {
            float pv[4] = {PHt0, PHt1, PHt2, PHt3};
            #pragma unroll
            for (int n = 0; n < 4; ++n) {
                unsigned short hh = f2bf(pv[n]);
                sPNh[n*36 + lane] = hh;
                sPNl[n*36 + lane] = f2bf(pv[n] - bf2f(hh));
            }
        }

        // mm[n] = H[n,:].m   (lanes 0-3; independent of MFMAs above)
        float mmv = 0.f;
        if (lane < 4) {
            #pragma unroll
            for (int q = 0; q < 8; ++q) {
                f4v hv = *(const f4v*)&sHf[lane*40 + 4*q];
                f4v mv = *(const f4v*)&sm[4*q];
                mmv += hv.x*mv.x + hv.y*mv.y + hv.z*mv.z + hv.w*mv.w;
            }
        }
        __syncthreads();

        // ===== Smeas = H*PHt + R via MFMA (B from sPN) =====
        bf8 Nh0, Nh1, Nl0, Nl1;
        if (c < 4) {
            Nh0 = ld8(&sPNh[c*36 + h*8]);
            Nh1 = ld8(&sPNh[c*36 + 16 + h*8]);
            Nl0 = ld8(&sPNl[c*36 + h*8]);
            Nl1 = ld8(&sPNl[c*36 + 16 + h*8]);
        } else {
            Nh0 = (bf8)(short)0; Nh1 = (bf8)(short)0;
            Nl0 = (bf8)(short)0; Nl1 = (bf8)(short)0;
        }
        f16v sA = 0.0f, sB = 0.0f;
        sA = MFMA(Hh[0], Nh0, sA);
        sB = MFMA(Hh[1], Nh1, sB);
        sA = MFMA(Hh[0], Nl0, sA);
        sB = MFMA(Hh[1], Nl1, sB);
        sA = MFMA(Hl[0], Nh0, sA);
        sB = MFMA(Hl[1], Nh1, sB);

        // outputs: mc rows (lane c<4 holds Sm[m][c]), mm, resid
        if (lane < 32 && c < 4) {
            #pragma unroll
            for (int m = 0; m < 4; ++m) {
                float s = sA[m] + sB[m] + Rc[m];
                out_covs[(((size_t)t*BB + b)*4 + m)*4 + c] = s;
                sSm[m*4 + c] = s;
            }
        }
        if (lane < 4) {
            out_means[((size_t)t*BB + b)*4 + lane] = mmv;
            sresid[lane] = yv - mmv;
        }
        if (t == TT - 1) break;
        __syncthreads();

        // ===== 4x4 inverse (Cramer, redundant on lanes<32) + gain rows G =====
        float G0, G1, G2, G3;
        {
            f4v Ma = *(const f4v*)&sSm[0];
            f4v Mb = *(const f4v*)&sSm[4];
            f4v Mc = *(const f4v*)&sSm[8];
            f4v Md = *(const f4v*)&sSm[12];
            const float M0 = Ma.x, M1 = Ma.y, M2 = Ma.z, M3 = Ma.w;
            const float M4 = Mb.x, M5 = Mb.y, M6 = Mb.z, M7 = Mb.w;
            const float M8 = Mc.x, M9 = Mc.y, M10 = Mc.z, M11 = Mc.w;
            const float M12 = Md.x, M13 = Md.y, M14 = Md.z, M15 = Md.w;

            const float A2323 = M10*M15 - M11*M14;
            const float A1323 = M9 *M15 - M11*M13;
            const float A1223 = M9 *M14 - M10*M13;
            const float A0323 = M8 *M15 - M11*M12;
            const float A0223 = M8 *M14 - M10*M12;
            const float A0123 = M8 *M13 - M9 *M12;
            const float A2313 = M6 *M15 - M7 *M14;
            const float A1313 = M5 *M15 - M7 *M13;
            const float A1213 = M5 *M14 - M6 *M13;
            const float A2312 = M6 *M11 - M7 *M10;
            const float A1312 = M5 *M11 - M7 *M9;
            const float A1212 = M5 *M10 - M6 *M9;
            const float A0313 = M4 *M15 - M7 *M12;
            const float A0213 = M4 *M14 - M6 *M12;
            const float A0312 = M4 *M11 - M7 *M8;
            const float A0212 = M4 *M10 - M6 *M8;
            const float A0113 = M4 *M13 - M5 *M12;
            const float A0112 = M4 *M9  - M5 *M8;

            const float i00 =  (M5*A2323 - M6*A1323 + M7*A1223);
            const float i10 = -(M4*A2323 - M6*A0323 + M7*A0223);
            const float i20 =  (M4*A1323 - M5*A0323 + M7*A0123);
            const float i30 = -(M4*A1223 - M5*A0223 + M6*A0123);
            const float i01 = -(M1*A2323 - M2*A1323 + M3*A1223);
            const float i11 =  (M0*A2323 - M2*A0323 + M3*A0223);
            const float i21 = -(M0*A1323 - M1*A0323 + M3*A0123);
            const float i31 =  (M0*A1223 - M1*A0223 + M2*A0123);
            const float i02 =  (M1*A2313 - M2*A1313 + M3*A1213);
            const float i12 = -(M0*A2313 - M2*A0313 + M3*A0213);
            const float i22 =  (M0*A1313 - M1*A0313 + M3*A0113);
            const float i32 = -(M0*A1213 - M1*A0213 + M2*A0113);
            const float i03 = -(M1*A2312 - M2*A1312 + M3*A1212);
            const float i13 =  (M0*A2312 - M2*A0312 + M3*A0212);
            const float i23 = -(M0*A1312 - M1*A0312 + M3*A0112);
            const float i33 =  (M0*A1212 - M1*A0212 + M2*A0112);

            const float det = M0*i00 + M1*i10 + M2*i20 + M3*i30;
            const float invdet = 1.0f / det;

            G0 = invdet * (PHt0*i00 + PHt1*i10 + PHt2*i20 + PHt3*i30);
            G1 = invdet * (PHt0*i01 + PHt1*i11 + PHt2*i21 + PHt3*i31);
            G2 = invdet * (PHt0*i02 + PHt1*i12 + PHt2*i22 + PHt3*i32);
            G3 = invdet * (PHt0*i03 + PHt1*i13 + PHt2*i23 + PHt3*i33);
        }

        // mean update: m_u = m + G.resid  (lanes<32)
        {
            f4v rv = *(const f4v*)&sresid[0];
            float mu = mreg + G0*rv.x + G1*rv.y + G2*rv.z + G3*rv.w;
            if (lane < 32) smu[lane] = mu;
        }

        // ===== P_u = P - G*PHt^T : rank-4 MFMA fully in registers =====
        bf8 nGh = (bf8)(short)0, nGl = (bf8)(short)0;
        bf8 Bth = (bf8)(short)0, Btl = (bf8)(short)0;
        if (h == 0) {
            float gv[4] = {-G0, -G1, -G2, -G3};
            float pv[4] = {PHt0, PHt1, PHt2, PHt3};
            #pragma unroll
            for (int j = 0; j < 4; ++j) {
                unsigned short gh = f2bf(gv[j]);
                nGh[j] = (short)gh;
                nGl[j] = (short)f2bf(gv[j] - bf2f(gh));
                unsigned short ph = f2bf(pv[j]);
                Bth[j] = (short)ph;
                Btl[j] = (short)f2bf(pv[j] - bf2f(ph));
            }
        }
        f16v Pu = P;
        Pu = MFMA(nGh, Bth, Pu);
        Pu = MFMA(nGh, Btl, Pu);
        Pu = MFMA(nGl, Bth, Pu);

        // write P_u (symmetric) to work buffer as bf16 hi/lo
        #pragma unroll
        for (int q = 0; q < 4; ++q) {
            int r0 = 8*q + 4*h;
            bf4 vh, vl;
            #pragma unroll
            for (int i = 0; i < 4; ++i) {
                float x = Pu[4*q + i];
                unsigned short hh = f2bf(x);
                vh[i] = (short)hh;
                vl[i] = (short)f2bf(x - bf2f(hh));
            }
            *(bf4*)&sWBh[c*36 + r0] = vh;
            *(bf4*)&sWBl[c*36 + r0] = vl;
        }
        __syncthreads();

        // m_p = F*m_u  (lanes<32; overlaps with MFMA traffic)
        {
            float mp = 0.f;
            #pragma unroll
            for (int q = 0; q < 8; ++q) {
                f4v fv = *(const f4v*)&sFf[(lane & 31)*40 + 4*q];
                f4v mv = *(const f4v*)&smu[4*q];
                mp += fv.x*mv.x + fv.y*mv.y + fv.z*mv.z + fv.w*mv.w;
            }
            if (lane < 32) { mreg = mp; sm[lane] = mp; }
        }

        // ===== T' = P_u * F^T  (A = P_u frags, B = F frags) =====
        bf8 Ah0, Ah1, Al0, Al1;
        Ah0 = ld8(&sWBh[c*36 + h*8]);
        Ah1 = ld8(&sWBh[c*36 + 16 + h*8]);
        Al0 = ld8(&sWBl[c*36 + h*8]);
        Al1 = ld8(&sWBl[c*36 + 16 + h*8]);
        f16v tA = 0.0f, tB = 0.0f;
        tA = MFMA(Ah0, Fh[0], tA);
        tB = MFMA(Ah1, Fh[1], tB);
        tA = MFMA(Ah0, Fl[0], tA);
        tB = MFMA(Ah1, Fl[1], tB);
        tA = MFMA(Al0, Fh[0], tA);
        tB = MFMA(Al1, Fh[1], tB);
        f16v Tp = tA + tB;
        __syncthreads();

        // write T' to work buffer: storage [c][r] = T'[r][c] (B-frag layout for F*T')
        #pragma unroll
        for (int q = 0; q < 4; ++q) {
            int r0 = 8*q + 4*h;
            bf4 vh, vl;
            #pragma unroll
            for (int i = 0; i < 4; ++i) {
                float x = Tp[4*q + i];
                unsigned short hh = f2bf(x);
                vh[i] = (short)hh;
                vl[i] = (short)f2bf(x - bf2f(hh));
            }
            *(bf4*)&sWBh[c*36 + r0] = vh;
            *(bf4*)&sWBl[c*36 + r0] = vl;
        }
        __syncthreads();

        // ===== P_p = F * T' + Q =====
        bf8 Th0, Th1, Tl0, Tl1;
        Th0 = ld8(&sWBh[c*36 + h*8]);
        Th1 = ld8(&sWBh[c*36 + 16 + h*8]);
        Tl0 = ld8(&sWBl[c*36 + h*8]);
        Tl1 = ld8(&sWBl[c*36 + 16 + h*8]);
        f16v pA = Qc, pB = 0.0f;
        pA = MFMA(Fh[0], Th0, pA);
        pB = MFMA(Fh[1], Th1, pB);
        pA = MFMA(Fh[0], Tl0, pA);
        pB = MFMA(Fh[1], Tl1, pB);
        pA = MFMA(Fl[0], Th0, pA);
        pB = MFMA(Fl[1], Th1, pB);
        P = pA + pB;

        // write P_p bf16 frags for next step (symmetric store)
        #pragma unroll
        for (int q = 0; q < 4; ++q) {
            int r0 = 8*q + 4*h;
            bf4 vh, vl;
            #pragma unroll
            for (int i = 0; i < 4; ++i) {
                float x = P[4*q + i];
                unsigned short hh = f2bf(x);
                vh[i] = (short)hh;
                vl[i] = (short)f2bf(x - bf2f(hh));
            }
            *(bf4*)&sPBh[c*36 + r0] = vh;
            *(bf4*)&sPBl[c*36 + r0] = vl;
        }
        __syncthreads();
    }
}

extern "C" void kernel_launch(void* const* d_in, const int* in_sizes, int n_in,
                              void* d_out, int out_size, void* d_ws, size_t ws_size,
                              hipStream_t stream) {
    const float* obs       = (const float*)d_in[0];
    const float* F         = (const float*)d_in[1];
    const float* Q         = (const float*)d_in[2];
    const float* H         = (const float*)d_in[3];
    const float* R         = (const float*)d_in[4];
    const float* init_mean = (const float*)d_in[5];
    const float* init_cov  = (const float*)d_in[6];
    float* out = (float*)d_out;

    kalman_wave<<<BB, 64, 0, stream>>>(obs, F, Q, H, R, init_mean, init_cov, out);
}

// Round 4
// 588.043 us; speedup vs baseline: 1.4420x; 1.4420x over previous
//
#include <hip/hip_runtime.h>

#define BB 512
#define TT 256

typedef __attribute__((ext_vector_type(8)))  short bf8;   // 8 bf16 in 4 VGPRs
typedef __attribute__((ext_vector_type(4)))  short bf4;   // 4 bf16, 8B
typedef __attribute__((ext_vector_type(16))) float f16v;  // MFMA 32x32 acc
typedef __attribute__((ext_vector_type(4)))  float f4v;

#define MFMA(a,b,c) __builtin_amdgcn_mfma_f32_32x32x16_bf16((a),(b),(c),0,0,0)

static __device__ __forceinline__ unsigned short f2bf_rne(float x) {
    unsigned u = __builtin_bit_cast(unsigned, x);
    return (unsigned short)((u + 0x7FFFu + ((u >> 16) & 1u)) >> 16);
}
static __device__ __forceinline__ float bf2f(unsigned short h) {
    unsigned u = ((unsigned)h) << 16;
    return __builtin_bit_cast(float, u);
}
// cheap truncation-based hi/lo split: |x - (hi+lo)| <~ 2^-17 |x|
static __device__ __forceinline__ void tsplit(float x, short& hi, short& lo) {
    unsigned u = __builtin_bit_cast(unsigned, x);
    hi = (short)(u >> 16);
    float hf = __builtin_bit_cast(float, u & 0xFFFF0000u);
    float l  = x - hf;
    lo = (short)(__builtin_bit_cast(unsigned, l) >> 16);
}
static __device__ __forceinline__ bf8 ld8(const unsigned short* p) {
    bf4 a = *(const bf4*)p;
    bf4 b = *(const bf4*)(p + 4);
    bf8 r;
    r[0]=a[0]; r[1]=a[1]; r[2]=a[2]; r[3]=a[3];
    r[4]=b[0]; r[5]=b[1]; r[6]=b[2]; r[7]=b[3];
    return r;
}

// One chain per wave. Critical-path-minimized step:
//   P_p = (F P F^T + Q) - W Sinv W^T,  W = F P H^T  — Cramer parallel to the Z arm.
// C-layout: lane (c,h) reg r holds D[(r&3)+8(r>>2)+4h][c].
// A/B-frag: lane (c,h) holds M[c][16kk+8h+j].
__global__ __launch_bounds__(64)
void kalman_v4(const float* __restrict__ obs,
               const float* __restrict__ Fg,
               const float* __restrict__ Qg,
               const float* __restrict__ Hg,
               const float* __restrict__ Rg,
               const float* __restrict__ im,
               const float* __restrict__ ic,
               float* __restrict__ out)
{
    __shared__ __align__(16) unsigned short sT1h[32*36], sT1l[32*36]; // T1=P*F^T, [c][r]
    __shared__ __align__(16) unsigned short sPNh[4*36],  sPNl[4*36];  // [n][k] = PHt[k][n]
    __shared__ __align__(16) float sFH[36*40];   // rows 0-31: F, rows 32-35: H
    __shared__ __align__(16) float sm[32];

    const int lane = threadIdx.x;
    const int b    = blockIdx.x;
    const int c    = lane & 31;
    const int h    = lane >> 5;

    bf8 Fh[2], Fl[2], Hh[2], Hl[2];
    #pragma unroll
    for (int kk = 0; kk < 2; ++kk) {
        #pragma unroll
        for (int j = 0; j < 8; ++j) {
            int k = kk*16 + h*8 + j;
            float f = Fg[c*32 + k];
            unsigned short fh = f2bf_rne(f);
            Fh[kk][j] = (short)fh;
            Fl[kk][j] = (short)f2bf_rne(f - bf2f(fh));
            float hv = (c < 4) ? Hg[c*32 + k] : 0.f;
            unsigned short hh = f2bf_rne(hv);
            Hh[kk][j] = (short)hh;
            Hl[kk][j] = (short)f2bf_rne(hv - bf2f(hh));
        }
    }

    f16v Qc, P;
    #pragma unroll
    for (int reg = 0; reg < 16; ++reg) {
        int row = (reg & 3) + 8*(reg >> 2) + 4*h;
        Qc[reg] = Qg[row*32 + c];
        P[reg]  = ic[(size_t)b*1024 + row*32 + c];
    }
    float Rc[4] = {0.f, 0.f, 0.f, 0.f};
    if (c < 4) {
        #pragma unroll
        for (int m = 0; m < 4; ++m) Rc[m] = Rg[m*4 + c];
    }

    #pragma unroll
    for (int e = lane; e < 1024; e += 64) sFH[(e >> 5)*40 + (e & 31)] = Fg[e];
    #pragma unroll
    for (int e = lane; e < 128; e += 64) sFH[(32 + (e >> 5))*40 + (e & 31)] = Hg[e];
    if (lane < 32) sm[lane] = im[b*32 + lane];
    __syncthreads();

    const float* dotrow = &sFH[(lane < 32 ? lane : (32 + (lane & 3))) * 40];
    float* om = out;
    float* oc = out + (size_t)TT * BB * 4;

    for (int t = 0; t < TT; ++t) {
        float yv = 0.f;
        if (lane >= 32 && lane < 36) yv = obs[((size_t)b*TT + t)*4 + (lane - 32)];

        // lanes<32: Fm[lane];  lanes>=32: mm[lane&3]
        float dotv = 0.f;
        #pragma unroll
        for (int q = 0; q < 8; ++q) {
            f4v a = *(const f4v*)&dotrow[4*q];
            f4v mv = *(const f4v*)&sm[4*q];
            dotv += a.x*mv.x + a.y*mv.y + a.z*mv.z + a.w*mv.w;
        }

        // build P frag from C-layout regs via lane^32 exchange (P symmetric)
        float p2[16];
        #pragma unroll
        for (int r = 0; r < 16; ++r) p2[r] = __shfl_xor(P[r], 32, 64);
        float fr[2][8];
        #pragma unroll
        for (int j = 0; j < 4; ++j) {
            fr[0][j]   = h ? p2[4+j]  : P[j];
            fr[0][4+j] = h ? P[4+j]   : p2[j];
            fr[1][j]   = h ? p2[12+j] : P[8+j];
            fr[1][4+j] = h ? P[12+j]  : p2[8+j];
        }
        bf8 Ph[2], Pl[2];
        #pragma unroll
        for (int kk = 0; kk < 2; ++kk)
            #pragma unroll
            for (int j = 0; j < 8; ++j) {
                short hi, lo;
                tsplit(fr[kk][j], hi, lo);
                Ph[kk][j] = hi;
                Pl[kk][j] = lo;
            }

        // T1 = P*F^T  and  PHt = (H*P)^T
        f16v tA = 0.0f, tB = 0.0f;
        tA = MFMA(Ph[0], Fh[0], tA);  tB = MFMA(Ph[1], Fh[1], tB);
        tA = MFMA(Ph[0], Fl[0], tA);  tB = MFMA(Ph[1], Fl[1], tB);
        tA = MFMA(Pl[0], Fh[0], tA);  tB = MFMA(Pl[1], Fh[1], tB);

        f16v aA = 0.0f, aB = 0.0f;
        aA = MFMA(Hh[0], Ph[0], aA);  aB = MFMA(Hh[1], Ph[1], aB);
        aA = MFMA(Hh[0], Pl[0], aA);  aB = MFMA(Hh[1], Pl[1], aB);
        aA = MFMA(Hl[0], Ph[0], aA);  aB = MFMA(Hl[1], Ph[1], aB);

        if (lane < 32) {
            #pragma unroll
            for (int n = 0; n < 4; ++n) {
                short hi, lo;
                tsplit(aA[n] + aB[n], hi, lo);
                sPNh[n*36 + c] = (unsigned short)hi;
                sPNl[n*36 + c] = (unsigned short)lo;
            }
        }
        {
            f16v Tp = tA + tB;
            #pragma unroll
            for (int q = 0; q < 4; ++q) {
                int r0 = 8*q + 4*h;
                bf4 vh, vl;
                #pragma unroll
                for (int i = 0; i < 4; ++i) {
                    short hi, lo;
                    tsplit(Tp[4*q + i], hi, lo);
                    vh[i] = hi; vl[i] = lo;
                }
                *(bf4*)&sT1h[c*36 + r0] = vh;
                *(bf4*)&sT1l[c*36 + r0] = vl;
            }
        }
        __syncthreads();  // B1

        bf8 N0h, N1h, N0l, N1l;
        if (c < 4) {
            N0h = ld8(&sPNh[c*36 + 8*h]);
            N1h = ld8(&sPNh[c*36 + 16 + 8*h]);
            N0l = ld8(&sPNl[c*36 + 8*h]);
            N1l = ld8(&sPNl[c*36 + 16 + 8*h]);
        } else {
            N0h = (bf8)(short)0; N1h = (bf8)(short)0;
            N0l = (bf8)(short)0; N1l = (bf8)(short)0;
        }
        bf8 T0h = ld8(&sT1h[c*36 + 8*h]);
        bf8 T1h_ = ld8(&sT1h[c*36 + 16 + 8*h]);
        bf8 T0l = ld8(&sT1l[c*36 + 8*h]);
        bf8 T1l_ = ld8(&sT1l[c*36 + 16 + 8*h]);

        f16v sA = 0.0f, sB = 0.0f;
        sA = MFMA(Hh[0], N0h, sA);  sB = MFMA(Hh[1], N1h, sB);
        sA = MFMA(Hh[0], N0l, sA);  sB = MFMA(Hh[1], N1l, sB);
        sA = MFMA(Hl[0], N0h, sA);  sB = MFMA(Hl[1], N1h, sB);

        f16v wA = 0.0f, wB = 0.0f;
        wA = MFMA(N0h, Fh[0], wA);  wB = MFMA(N1h, Fh[1], wB);
        wA = MFMA(N0h, Fl[0], wA);  wB = MFMA(N1h, Fl[1], wB);
        wA = MFMA(N0l, Fh[0], wA);  wB = MFMA(N1l, Fh[1], wB);

        f16v zA = Qc, zB = 0.0f;
        zA = MFMA(Fh[0], T0h, zA);  zB = MFMA(Fh[1], T1h_, zB);
        zA = MFMA(Fh[0], T0l, zA);  zB = MFMA(Fh[1], T1l_, zB);
        zA = MFMA(Fl[0], T0h, zA);  zB = MFMA(Fl[1], T1h_, zB);

        float Smr[4];
        #pragma unroll
        for (int m = 0; m < 4; ++m) Smr[m] = sA[m] + sB[m] + Rc[m];
        if (lane < 32 && c < 4) {
            #pragma unroll
            for (int m = 0; m < 4; ++m)
                oc[(((size_t)t*BB + b)*4 + m)*4 + c] = Smr[m];
        }
        float residv = yv - dotv;  // lanes 32-35
        if (lane >= 32 && lane < 36)
            om[((size_t)t*BB + b)*4 + (lane - 32)] = dotv;

        if (t == TT - 1) break;

        float S0  = __shfl(Smr[0], 0, 64), S1  = __shfl(Smr[0], 1, 64),
              S2  = __shfl(Smr[0], 2, 64), S3  = __shfl(Smr[0], 3, 64);
        float S4  = __shfl(Smr[1], 0, 64), S5  = __shfl(Smr[1], 1, 64),
              S6  = __shfl(Smr[1], 2, 64), S7  = __shfl(Smr[1], 3, 64);
        float S8  = __shfl(Smr[2], 0, 64), S9  = __shfl(Smr[2], 1, 64),
              S10 = __shfl(Smr[2], 2, 64), S11 = __shfl(Smr[2], 3, 64);
        float S12 = __shfl(Smr[3], 0, 64), S13 = __shfl(Smr[3], 1, 64),
              S14 = __shfl(Smr[3], 2, 64), S15 = __shfl(Smr[3], 3, 64);

        float nG0, nG1, nG2, nG3, W0, W1, W2, W3;
        {
            const float A2323 = S10*S15 - S11*S14;
            const float A1323 = S9 *S15 - S11*S13;
            const float A1223 = S9 *S14 - S10*S13;
            const float A0323 = S8 *S15 - S11*S12;
            const float A0223 = S8 *S14 - S10*S12;
            const float A0123 = S8 *S13 - S9 *S12;
            const float A2313 = S6 *S15 - S7 *S14;
            const float A1313 = S5 *S15 - S7 *S13;
            const float A1213 = S5 *S14 - S6 *S13;
            const float A2312 = S6 *S11 - S7 *S10;
            const float A1312 = S5 *S11 - S7 *S9;
            const float A1212 = S5 *S10 - S6 *S9;
            const float A0313 = S4 *S15 - S7 *S12;
            const float A0213 = S4 *S14 - S6 *S12;
            const float A0312 = S4 *S11 - S7 *S8;
            const float A0212 = S4 *S10 - S6 *S8;
            const float A0113 = S4 *S13 - S5 *S12;
            const float A0112 = S4 *S9  - S5 *S8;

            const float i00 =  (S5*A2323 - S6*A1323 + S7*A1223);
            const float i10 = -(S4*A2323 - S6*A0323 + S7*A0223);
            const float i20 =  (S4*A1323 - S5*A0323 + S7*A0123);
            const float i30 = -(S4*A1223 - S5*A0223 + S6*A0123);
            const float i01 = -(S1*A2323 - S2*A1323 + S3*A1223);
            const float i11 =  (S0*A2323 - S2*A0323 + S3*A0223);
            const float i21 = -(S0*A1323 - S1*A0323 + S3*A0123);
            const float i31 =  (S0*A1223 - S1*A0223 + S2*A0123);
            const float i02 =  (S1*A2313 - S2*A1313 + S3*A1213);
            const float i12 = -(S0*A2313 - S2*A0313 + S3*A0213);
            const float i22 =  (S0*A1313 - S1*A0313 + S3*A0113);
            const float i32 = -(S0*A1213 - S1*A0213 + S2*A0113);
            const float i03 = -(S1*A2312 - S2*A1312 + S3*A1212);
            const float i13 =  (S0*A2312 - S2*A0312 + S3*A0212);
            const float i23 = -(S0*A1312 - S1*A0312 + S3*A0112);
            const float i33 =  (S0*A1212 - S1*A0212 + S2*A0112);

            const float det = S0*i00 + S1*i10 + S2*i20 + S3*i30;
            const float nid = -1.0f / det;   // negative -> nG = -W*Sinv

            W0 = wA[0] + wB[0];
            W1 = wA[1] + wB[1];
            W2 = wA[2] + wB[2];
            W3 = wA[3] + wB[3];

            nG0 = nid * (W0*i00 + W1*i10 + W2*i20 + W3*i30);
            nG1 = nid * (W0*i01 + W1*i11 + W2*i21 + W3*i31);
            nG2 = nid * (W0*i02 + W1*i12 + W2*i22 + W3*i32);
            nG3 = nid * (W0*i03 + W1*i13 + W2*i23 + W3*i33);
        }

        bf8 Gh = (bf8)(short)0, Gl = (bf8)(short)0;
        bf8 Wbh = (bf8)(short)0, Wbl = (bf8)(short)0;
        {
            float ng[4] = {nG0, nG1, nG2, nG3};
            float wv[4] = {W0, W1, W2, W3};
            #pragma unroll
            for (int j2 = 0; j2 < 4; ++j2) {
                short hi, lo;
                tsplit(ng[j2], hi, lo);
                Gh[j2] = hi; Gl[j2] = lo;
                tsplit(wv[j2], hi, lo);
                Wbh[j2] = hi; Wbl[j2] = lo;
            }
        }
        f16v Pn = zA + zB;
        Pn = MFMA(Gh, Wbh, Pn);
        Pn = MFMA(Gh, Wbl, Pn);
        Pn = MFMA(Gl, Wbh, Pn);
        P = Pn;

        float r0 = __shfl(residv, 32, 64), r1 = __shfl(residv, 33, 64);
        float r2 = __shfl(residv, 34, 64), r3 = __shfl(residv, 35, 64);
        if (lane < 32)
            sm[lane] = dotv - (nG0*r0 + nG1*r1 + nG2*r2 + nG3*r3);
        __syncthreads();  // B2
    }
}

extern "C" void kernel_launch(void* const* d_in, const int* in_sizes, int n_in,
                              void* d_out, int out_size, void* d_ws, size_t ws_size,
                              hipStream_t stream) {
    const float* obs       = (const float*)d_in[0];
    const float* F         = (const float*)d_in[1];
    const float* Q         = (const float*)d_in[2];
    const float* H         = (const float*)d_in[3];
    const float* R         = (const float*)d_in[4];
    const float* init_mean = (const float*)d_in[5];
    const float* init_cov  = (const float*)d_in[6];
    float* out = (float*)d_out;

    kalman_v4<<<BB, 64, 0, stream>>>(obs, F, Q, H, R, init_mean, init_cov, out);
}

// Round 5
// 540.663 us; speedup vs baseline: 1.5684x; 1.0876x over previous
//
#include <hip/hip_runtime.h>

#define BB 512
#define TT 256

typedef __attribute__((ext_vector_type(8)))  short bf8;   // 8 bf16 in 4 VGPRs
typedef __attribute__((ext_vector_type(4)))  short bf4;   // 4 bf16, 8B
typedef __attribute__((ext_vector_type(16))) float f16v;  // MFMA 32x32 acc
typedef __attribute__((ext_vector_type(4)))  float f4v;

#define MFMA(a,b,c) __builtin_amdgcn_mfma_f32_32x32x16_bf16((a),(b),(c),0,0,0)

static __device__ __forceinline__ unsigned short f2bf_rne(float x) {
    unsigned u = __builtin_bit_cast(unsigned, x);
    return (unsigned short)((u + 0x7FFFu + ((u >> 16) & 1u)) >> 16);
}
static __device__ __forceinline__ float bf2f(unsigned short h) {
    unsigned u = ((unsigned)h) << 16;
    return __builtin_bit_cast(float, u);
}
// truncation-based hi/lo split: |x - (hi+lo)| <~ 2^-17 |x|
static __device__ __forceinline__ void tsplit(float x, short& hi, short& lo) {
    unsigned u = __builtin_bit_cast(unsigned, x);
    hi = (short)(u >> 16);
    float hf = __builtin_bit_cast(float, u & 0xFFFF0000u);
    float l  = x - hf;
    lo = (short)(__builtin_bit_cast(unsigned, l) >> 16);
}
static __device__ __forceinline__ bf8 ld8(const unsigned short* p) {
    bf4 a = *(const bf4*)p;
    bf4 b = *(const bf4*)(p + 4);
    bf8 r;
    r[0]=a[0]; r[1]=a[1]; r[2]=a[2]; r[3]=a[3];
    r[4]=b[0]; r[5]=b[1]; r[6]=b[2]; r[7]=b[3];
    return r;
}

// One chain per wave; SINGLE-WAVE block => no __syncthreads needed anywhere:
// same-wave LDS ordering is guaranteed by in-order ds ops + lgkmcnt waits.
// Step:  P_p = (F P F^T + Q) - W Sinv W^T,  W = F P H^T  (Cramer parallel to Z arm).
// C-layout: lane (c,h) reg r holds D[(r&3)+8(r>>2)+4h][c].
// A/B-frag: lane (c,h) holds M[c][16kk+8h+j].
__global__ __launch_bounds__(64)
void kalman_v5(const float* __restrict__ obs,
               const float* __restrict__ Fg,
               const float* __restrict__ Qg,
               const float* __restrict__ Hg,
               const float* __restrict__ Rg,
               const float* __restrict__ im,
               const float* __restrict__ ic,
               float* __restrict__ out)
{
    __shared__ __align__(16) unsigned short sT1h[32*36], sT1l[32*36]; // T1=P*F^T, [c][r]
    __shared__ __align__(16) unsigned short sPNh[4*36],  sPNl[4*36];  // [n][k] = PHt[k][n]
    __shared__ __align__(16) float sFH[36*40];   // rows 0-31: F, rows 32-35: H
    __shared__ __align__(16) float sm[32];
    __shared__ __align__(16) float sS[16];       // sS[c*4+m] = Smeas[m][c]
    __shared__ __align__(16) float sRes4[4];

    const int lane = threadIdx.x;
    const int b    = blockIdx.x;
    const int c    = lane & 31;
    const int h    = lane >> 5;

    bf8 Fh[2], Fl[2], Hh[2], Hl[2];
    #pragma unroll
    for (int kk = 0; kk < 2; ++kk) {
        #pragma unroll
        for (int j = 0; j < 8; ++j) {
            int k = kk*16 + h*8 + j;
            float f = Fg[c*32 + k];
            unsigned short fh = f2bf_rne(f);
            Fh[kk][j] = (short)fh;
            Fl[kk][j] = (short)f2bf_rne(f - bf2f(fh));
            float hv = (c < 4) ? Hg[c*32 + k] : 0.f;
            unsigned short hh = f2bf_rne(hv);
            Hh[kk][j] = (short)hh;
            Hl[kk][j] = (short)f2bf_rne(hv - bf2f(hh));
        }
    }

    f16v Qc, P;
    #pragma unroll
    for (int reg = 0; reg < 16; ++reg) {
        int row = (reg & 3) + 8*(reg >> 2) + 4*h;
        Qc[reg] = Qg[row*32 + c];
        P[reg]  = ic[(size_t)b*1024 + row*32 + c];
    }
    float Rc[4] = {0.f, 0.f, 0.f, 0.f};
    if (c < 4) {
        #pragma unroll
        for (int m = 0; m < 4; ++m) Rc[m] = Rg[m*4 + c];
    }

    #pragma unroll
    for (int e = lane; e < 1024; e += 64) sFH[(e >> 5)*40 + (e & 31)] = Fg[e];
    #pragma unroll
    for (int e = lane; e < 128; e += 64) sFH[(32 + (e >> 5))*40 + (e & 31)] = Hg[e];
    if (lane < 32) sm[lane] = im[b*32 + lane];

    const float* dotrow = &sFH[(lane < 32 ? lane : (32 + (lane & 3))) * 40];
    const bool yl = (lane >= 32 && lane < 36);
    const float* obsp = obs + (size_t)b*TT*4 + (yl ? (lane - 32) : 0);
    float* om = out;
    float* oc = out + (size_t)TT * BB * 4;

    // software-pipelined observation load (consumed one step later)
    float yv = yl ? obsp[0] : 0.f;

    for (int t = 0; t < TT; ++t) {
        // issue next step's obs load NOW; consumed ~full step later
        float yv_nxt = (yl && t + 1 < TT) ? obsp[(t + 1) * 4] : 0.f;

        // lanes<32: Fm[lane];  lanes>=32: mm[lane&3]   (reads sm written last step)
        float dotv = 0.f;
        #pragma unroll
        for (int q = 0; q < 8; ++q) {
            f4v a = *(const f4v*)&dotrow[4*q];
            f4v mv = *(const f4v*)&sm[4*q];
            dotv += a.x*mv.x + a.y*mv.y + a.z*mv.z + a.w*mv.w;
        }

        // build P frag from C-layout regs via lane^32 exchange (P symmetric)
        float p2[16];
        #pragma unroll
        for (int r = 0; r < 16; ++r) p2[r] = __shfl_xor(P[r], 32, 64);
        float fr[2][8];
        #pragma unroll
        for (int j = 0; j < 4; ++j) {
            fr[0][j]   = h ? p2[4+j]  : P[j];
            fr[0][4+j] = h ? P[4+j]   : p2[j];
            fr[1][j]   = h ? p2[12+j] : P[8+j];
            fr[1][4+j] = h ? P[12+j]  : p2[8+j];
        }
        bf8 Ph[2], Pl[2];
        #pragma unroll
        for (int kk = 0; kk < 2; ++kk)
            #pragma unroll
            for (int j = 0; j < 8; ++j) {
                short hi, lo;
                tsplit(fr[kk][j], hi, lo);
                Ph[kk][j] = hi;
                Pl[kk][j] = lo;
            }

        // group 1: T1 = P*F^T   and   HP = H*P  (PHt^T)
        f16v tA = 0.0f, tB = 0.0f;
        tA = MFMA(Ph[0], Fh[0], tA);  tB = MFMA(Ph[1], Fh[1], tB);
        tA = MFMA(Ph[0], Fl[0], tA);  tB = MFMA(Ph[1], Fl[1], tB);
        tA = MFMA(Pl[0], Fh[0], tA);  tB = MFMA(Pl[1], Fh[1], tB);

        f16v aA = 0.0f, aB = 0.0f;
        aA = MFMA(Hh[0], Ph[0], aA);  aB = MFMA(Hh[1], Ph[1], aB);
        aA = MFMA(Hh[0], Pl[0], aA);  aB = MFMA(Hh[1], Pl[1], aB);
        aA = MFMA(Hl[0], Ph[0], aA);  aB = MFMA(Hl[1], Ph[1], aB);

        // scatter PHt rows: sPN[n][k=c]  (lanes h==0 hold PHt[c][0..3] in regs 0-3)
        if (lane < 32) {
            #pragma unroll
            for (int n = 0; n < 4; ++n) {
                short hi, lo;
                tsplit(aA[n] + aB[n], hi, lo);
                sPNh[n*36 + c] = (unsigned short)hi;
                sPNl[n*36 + c] = (unsigned short)lo;
            }
        }
        // write T1 C-layout rows: storage[c][row] (packed bf4 runs)
        {
            f16v Tp = tA + tB;
            #pragma unroll
            for (int q = 0; q < 4; ++q) {
                int r0 = 8*q + 4*h;
                bf4 vh, vl;
                #pragma unroll
                for (int i = 0; i < 4; ++i) {
                    short hi, lo;
                    tsplit(Tp[4*q + i], hi, lo);
                    vh[i] = hi; vl[i] = lo;
                }
                *(bf4*)&sT1h[c*36 + r0] = vh;
                *(bf4*)&sT1l[c*36 + r0] = vl;
            }
        }
        // (no barrier: same-wave LDS in-order + lgkmcnt)

        bf8 N0h, N1h, N0l, N1l;
        if (c < 4) {
            N0h = ld8(&sPNh[c*36 + 8*h]);
            N1h = ld8(&sPNh[c*36 + 16 + 8*h]);
            N0l = ld8(&sPNl[c*36 + 8*h]);
            N1l = ld8(&sPNl[c*36 + 16 + 8*h]);
        } else {
            N0h = (bf8)(short)0; N1h = (bf8)(short)0;
            N0l = (bf8)(short)0; N1l = (bf8)(short)0;
        }
        bf8 T0h = ld8(&sT1h[c*36 + 8*h]);
        bf8 T1h_ = ld8(&sT1h[c*36 + 16 + 8*h]);
        bf8 T0l = ld8(&sT1l[c*36 + 8*h]);
        bf8 T1l_ = ld8(&sT1l[c*36 + 16 + 8*h]);

        // group 2 (ordered Smeas -> W -> Z so Cramer overlaps W/Z completion)
        f16v sA = 0.0f, sB = 0.0f;
        sA = MFMA(Hh[0], N0h, sA);  sB = MFMA(Hh[1], N1h, sB);
        sA = MFMA(Hh[0], N0l, sA);  sB = MFMA(Hh[1], N1l, sB);
        sA = MFMA(Hl[0], N0h, sA);  sB = MFMA(Hl[1], N1h, sB);

        f16v wA = 0.0f, wB = 0.0f;
        wA = MFMA(N0h, Fh[0], wA);  wB = MFMA(N1h, Fh[1], wB);
        wA = MFMA(N0h, Fl[0], wA);  wB = MFMA(N1h, Fl[1], wB);
        wA = MFMA(N0l, Fh[0], wA);  wB = MFMA(N1l, Fh[1], wB);

        f16v zA = Qc, zB = 0.0f;
        zA = MFMA(Fh[0], T0h, zA);  zB = MFMA(Fh[1], T1h_, zB);
        zA = MFMA(Fh[0], T0l, zA);  zB = MFMA(Fh[1], T1l_, zB);
        zA = MFMA(Fl[0], T0h, zA);  zB = MFMA(Fl[1], T1h_, zB);

        // outputs + broadcast staging
        float Smr[4];
        #pragma unroll
        for (int m = 0; m < 4; ++m) Smr[m] = sA[m] + sB[m] + Rc[m];
        if (lane < 32 && c < 4) {
            #pragma unroll
            for (int m = 0; m < 4; ++m)
                oc[(((size_t)t*BB + b)*4 + m)*4 + c] = Smr[m];
            *(f4v*)&sS[c*4] = (f4v){Smr[0], Smr[1], Smr[2], Smr[3]};
        }
        if (yl) {
            om[((size_t)t*BB + b)*4 + (lane - 32)] = dotv;
            sRes4[lane - 32] = yv - dotv;
        }

        if (t == TT - 1) break;
        yv = yv_nxt;

        // Smeas via LDS broadcast: q[n] = col n = (S[0][n],S[1][n],S[2][n],S[3][n])
        f4v q0 = *(const f4v*)&sS[0];
        f4v q1 = *(const f4v*)&sS[4];
        f4v q2 = *(const f4v*)&sS[8];
        f4v q3 = *(const f4v*)&sS[12];
        const float S0=q0.x,  S1=q1.x,  S2=q2.x,  S3=q3.x;
        const float S4=q0.y,  S5=q1.y,  S6=q2.y,  S7=q3.y;
        const float S8=q0.z,  S9=q1.z,  S10=q2.z, S11=q3.z;
        const float S12=q0.w, S13=q1.w, S14=q2.w, S15=q3.w;

        float nG0, nG1, nG2, nG3, W0, W1, W2, W3;
        {
            const float A2323 = S10*S15 - S11*S14;
            const float A1323 = S9 *S15 - S11*S13;
            const float A1223 = S9 *S14 - S10*S13;
            const float A0323 = S8 *S15 - S11*S12;
            const float A0223 = S8 *S14 - S10*S12;
            const float A0123 = S8 *S13 - S9 *S12;
            const float A2313 = S6 *S15 - S7 *S14;
            const float A1313 = S5 *S15 - S7 *S13;
            const float A1213 = S5 *S14 - S6 *S13;
            const float A2312 = S6 *S11 - S7 *S10;
            const float A1312 = S5 *S11 - S7 *S9;
            const float A1212 = S5 *S10 - S6 *S9;
            const float A0313 = S4 *S15 - S7 *S12;
            const float A0213 = S4 *S14 - S6 *S12;
            const float A0312 = S4 *S11 - S7 *S8;
            const float A0212 = S4 *S10 - S6 *S8;
            const float A0113 = S4 *S13 - S5 *S12;
            const float A0112 = S4 *S9  - S5 *S8;

            const float i00 =  (S5*A2323 - S6*A1323 + S7*A1223);
            const float i10 = -(S4*A2323 - S6*A0323 + S7*A0223);
            const float i20 =  (S4*A1323 - S5*A0323 + S7*A0123);
            const float i30 = -(S4*A1223 - S5*A0223 + S6*A0123);
            const float i01 = -(S1*A2323 - S2*A1323 + S3*A1223);
            const float i11 =  (S0*A2323 - S2*A0323 + S3*A0223);
            const float i21 = -(S0*A1323 - S1*A0323 + S3*A0123);
            const float i31 =  (S0*A1223 - S1*A0223 + S2*A0123);
            const float i02 =  (S1*A2313 - S2*A1313 + S3*A1213);
            const float i12 = -(S0*A2313 - S2*A0313 + S3*A0213);
            const float i22 =  (S0*A1313 - S1*A0313 + S3*A0113);
            const float i32 = -(S0*A1213 - S1*A0213 + S2*A0113);
            const float i03 = -(S1*A2312 - S2*A1312 + S3*A1212);
            const float i13 =  (S0*A2312 - S2*A0312 + S3*A0212);
            const float i23 = -(S0*A1312 - S1*A0312 + S3*A0112);
            const float i33 =  (S0*A1212 - S1*A0212 + S2*A0112);

            const float det = S0*i00 + S1*i10 + S2*i20 + S3*i30;
            const float nid = -1.0f / det;   // nG = -W*Sinv

            W0 = wA[0] + wB[0];
            W1 = wA[1] + wB[1];
            W2 = wA[2] + wB[2];
            W3 = wA[3] + wB[3];

            nG0 = nid * (W0*i00 + W1*i10 + W2*i20 + W3*i30);
            nG1 = nid * (W0*i01 + W1*i11 + W2*i21 + W3*i31);
            nG2 = nid * (W0*i02 + W1*i12 + W2*i22 + W3*i32);
            nG3 = nid * (W0*i03 + W1*i13 + W2*i23 + W3*i33);
        }

        // rank-4 correction (h==1 lanes have W=0 -> nG=0 -> contribute zeros)
        bf8 Gh = (bf8)(short)0, Gl = (bf8)(short)0;
        bf8 Wbh = (bf8)(short)0, Wbl = (bf8)(short)0;
        {
            float ng[4] = {nG0, nG1, nG2, nG3};
            float wv[4] = {W0, W1, W2, W3};
            #pragma unroll
            for (int j2 = 0; j2 < 4; ++j2) {
                short hi, lo;
                tsplit(ng[j2], hi, lo);
                Gh[j2] = hi; Gl[j2] = lo;
                tsplit(wv[j2], hi, lo);
                Wbh[j2] = hi; Wbl[j2] = lo;
            }
        }
        f16v Pn = zA + zB;
        Pn = MFMA(Gh, Wbh, Pn);
        Pn = MFMA(Gh, Wbl, Pn);
        Pn = MFMA(Gl, Wbh, Pn);
        P = Pn;

        // mean: m_next = Fm - nG.resid   (lanes<32; dotv==Fm there)
        {
            f4v rv = *(const f4v*)&sRes4[0];
            if (lane < 32)
                sm[lane] = dotv - (nG0*rv.x + nG1*rv.y + nG2*rv.z + nG3*rv.w);
        }
    }
}

extern "C" void kernel_launch(void* const* d_in, const int* in_sizes, int n_in,
                              void* d_out, int out_size, void* d_ws, size_t ws_size,
                              hipStream_t stream) {
    const float* obs       = (const float*)d_in[0];
    const float* F         = (const float*)d_in[1];
    const float* Q         = (const float*)d_in[2];
    const float* H         = (const float*)d_in[3];
    const float* R         = (const float*)d_in[4];
    const float* init_mean = (const float*)d_in[5];
    const float* init_cov  = (const float*)d_in[6];
    float* out = (float*)d_out;

    kalman_v5<<<BB, 64, 0, stream>>>(obs, F, Q, H, R, init_mean, init_cov, out);
}